// Round 2
// baseline (177.864 us; speedup 1.0000x reference)
//
#include <hip/hip_runtime.h>
#include <hip/hip_bf16.h>

// MoE MLP: x[1,2048,768] fp32, router_w[16,768], w1[768,12288], w2[12288,768]
// out[1,2048,768] fp32.  Experts: 8x512 + 8x1024, top-8, normalized.
// Dense bf16 GEMMs (reference is dense+masked); comb folded into H.
// GEMM core: 128x256 tile, BK=64, 8 waves, dbuf LDS, 4-phase/K-tile schedule,
// XOR-swizzled LDS (T2), setprio around MFMA clusters (T5), 1 barrier/K-tile.

#define T_TOK 2048
#define D_EMB 768
#define W_TOT 12288
#define N_EXP 16

typedef __attribute__((ext_vector_type(4))) float f32x4;
typedef __attribute__((ext_vector_type(8))) short bf16x8;

typedef __attribute__((address_space(1))) const unsigned int as1c_u32;
typedef __attribute__((address_space(3))) unsigned int as3_u32;

__device__ __forceinline__ void gload16(const void* g, void* l) {
  __builtin_amdgcn_global_load_lds((as1c_u32*)g, (as3_u32*)l, 16, 0, 0);
}

__device__ __forceinline__ unsigned short f2bf(float f) {
  __hip_bfloat16 h = __float2bfloat16(f);
  return *reinterpret_cast<unsigned short*>(&h);
}

__device__ __forceinline__ float gelu_f(float x) {
  // jax.nn.gelu default (approximate=True, tanh form)
  float x3 = x * x * x;
  float a = 0.7978845608028654f * __builtin_fmaf(0.044715f, x3, x);
  a = fminf(fmaxf(a, -20.f), 20.f);
  float e = __expf(-2.0f * a);
  float t = (1.0f - e) / (1.0f + e);
  return 0.5f * x * (1.0f + t);
}

// ---------------- conversion kernels ----------------

__global__ __launch_bounds__(256) void cvt_bf16_kernel(
    const float* __restrict__ in, unsigned short* __restrict__ out, int n) {
  int i = (blockIdx.x * 256 + threadIdx.x) * 4;
  if (i >= n) return;
  float4 v = *(const float4*)(in + i);
  ushort4 o;
  o.x = f2bf(v.x); o.y = f2bf(v.y); o.z = f2bf(v.z); o.w = f2bf(v.w);
  *(ushort4*)(out + i) = o;
}

// in fp32 [R][C] -> out bf16 [C][R]
__global__ __launch_bounds__(256) void transpose_cvt_kernel(
    const float* __restrict__ in, unsigned short* __restrict__ out, int R, int C) {
  __shared__ float tile[32][33];
  int c0 = blockIdx.x * 32;
  int r0 = blockIdx.y * 32;
  int i = threadIdx.x;
  {
    int r = i >> 3, c4 = (i & 7) * 4;
    float4 v = *(const float4*)(in + (size_t)(r0 + r) * C + c0 + c4);
    tile[r][c4 + 0] = v.x; tile[r][c4 + 1] = v.y;
    tile[r][c4 + 2] = v.z; tile[r][c4 + 3] = v.w;
  }
  __syncthreads();
  {
    int c = i >> 3, r4 = (i & 7) * 4;
    ushort4 o;
    o.x = f2bf(tile[r4 + 0][c]);
    o.y = f2bf(tile[r4 + 1][c]);
    o.z = f2bf(tile[r4 + 2][c]);
    o.w = f2bf(tile[r4 + 3][c]);
    *(ushort4*)(out + (size_t)(c0 + c) * R + r0 + r4) = o;
  }
}

// ---------------- router ----------------

__global__ __launch_bounds__(256) void router_kernel(
    const float* __restrict__ x, const float* __restrict__ rw,
    float* __restrict__ comb) {
  int tid = threadIdx.x, lane = tid & 63, w = tid >> 6;
  int t = blockIdx.x * 4 + w;
  const float* xr = x + (size_t)t * D_EMB;
  float xv[12];
#pragma unroll
  for (int i = 0; i < 12; ++i) xv[i] = xr[lane + 64 * i];
  float lg[16];
#pragma unroll
  for (int e = 0; e < 16; ++e) {
    const float* we = rw + (size_t)e * D_EMB;
    float p = 0.f;
#pragma unroll
    for (int i = 0; i < 12; ++i) p = __builtin_fmaf(xv[i], we[lane + 64 * i], p);
#pragma unroll
    for (int off = 32; off >= 1; off >>= 1) p += __shfl_xor(p, off, 64);
    lg[e] = p;
  }
  float mx = lg[0];
#pragma unroll
  for (int e = 1; e < 16; ++e) mx = fmaxf(mx, lg[e]);
  float ex[16];
#pragma unroll
  for (int e = 0; e < 16; ++e) ex[e] = __expf(lg[e] - mx);
  float selsum = 0.f, myval = 0.f;
#pragma unroll
  for (int e = 0; e < 16; ++e) {
    int rank = 0;
#pragma unroll
    for (int e2 = 0; e2 < 16; ++e2)
      rank += (ex[e2] > ex[e]) || (ex[e2] == ex[e] && e2 < e);
    bool sel = rank < 8;
    float v = sel ? ex[e] : 0.f;
    selsum += v;
    if (e == lane) myval = v;
  }
  if (lane < 16) comb[(size_t)t * N_EXP + lane] = myval / selsum;
}

// ---------------- unified 8-wave pipelined GEMM core ----------------
// C[BM=128][BN=256] per block; A row-major [M][lda], B N-major [N][ldb] (both
// bf16, K contiguous). 8 waves as 2(M) x 4(N); per-wave 64x64 out.
// EPI==1: H = gelu(acc) * comb  (bf16 store).  EPI==0: fp32 partial store.

template <int EPI>
__global__ __launch_bounds__(512, 2) void gemm8p_kernel(
    const unsigned short* __restrict__ Ag, const unsigned short* __restrict__ Bg,
    int lda, int ldb, int ntiles, int kchunk,
    const float* __restrict__ comb, unsigned short* __restrict__ hout,
    float* __restrict__ pout) {
  __shared__ __align__(16) char Ash[2][16384];   // [128 rows][64 k] bf16
  __shared__ __align__(16) char Bsh[2][32768];   // [256 rows][64 k] bf16
  __shared__ float Cw[EPI ? 128 * 16 : 16];

  const int tid = threadIdx.x;
  const int lane = tid & 63;
  const int wid = tid >> 6;
  const int wr = wid >> 2;        // 0..1  (M)
  const int wc = wid & 3;         // 0..3  (N)
  const int rm0 = blockIdx.y * 128;
  const int cn0 = blockIdx.x * 256;
  const int kbeg = blockIdx.z * kchunk;

  if constexpr (EPI == 1) {
    int row = tid >> 2, c4 = (tid & 3) * 4;
    *(float4*)&Cw[row * 16 + c4] =
        *(const float4*)(comb + (size_t)(rm0 + row) * N_EXP + c4);
  }

  // ---- staging (pre-swizzled global source, linear LDS dest) ----
  // LDS slot (row, inrow byte) holds global (row, inrow ^ ((row&7)<<4)).
  auto stageA = [&](int buf, int j, int kt) {
    int off = j * 8192 + tid * 16;
    int row = off >> 7, inrow = off & 127;
    int scol = inrow ^ ((row & 7) << 4);
    const char* src = (const char*)Ag +
        ((size_t)(rm0 + row) * lda + (kbeg + kt * 64)) * 2 + scol;
    gload16(src, Ash[buf] + j * 8192 + wid * 1024);
  };
  auto stageB = [&](int buf, int j, int kt) {
    int off = j * 8192 + tid * 16;
    int row = off >> 7, inrow = off & 127;
    int scol = inrow ^ ((row & 7) << 4);
    const char* src = (const char*)Bg +
        ((size_t)(cn0 + row) * ldb + (kbeg + kt * 64)) * 2 + scol;
    gload16(src, Bsh[buf] + j * 8192 + wid * 1024);
  };
  auto rdA = [&](int buf, int m, int kk) {
    int row = wr * 64 + m * 16 + (lane & 15);
    int col = (kk * 64 + (lane >> 4) * 16) ^ ((row & 7) << 4);
    return *(const bf16x8*)(Ash[buf] + row * 128 + col);
  };
  auto rdB = [&](int buf, int n, int kk) {
    int row = wc * 64 + n * 16 + (lane & 15);
    int col = (kk * 64 + (lane >> 4) * 16) ^ ((row & 7) << 4);
    return *(const bf16x8*)(Bsh[buf] + row * 128 + col);
  };

  f32x4 acc[4][4];
#pragma unroll
  for (int m = 0; m < 4; ++m)
#pragma unroll
    for (int n = 0; n < 4; ++n) acc[m][n] = (f32x4){0.f, 0.f, 0.f, 0.f};

  // prologue: stage tile 0 into buf 0
  stageA(0, 0, 0); stageB(0, 0, 0);
  stageA(0, 1, 0); stageB(0, 1, 0);
  stageB(0, 2, 0); stageB(0, 3, 0);
  asm volatile("s_waitcnt vmcnt(0) lgkmcnt(0)" ::: "memory");
  __builtin_amdgcn_s_barrier();
  __builtin_amdgcn_sched_barrier(0);

  int cur = 0;
  for (int t = 0; t < ntiles; ++t) {
    const int nxt = cur ^ 1;
    const bool pf = (t + 1 < ntiles);
    bf16x8 af[2][2], bf[4][2];

    // ---- phase 0: mh=0, nh=0 ----
#pragma unroll
    for (int mi = 0; mi < 2; ++mi)
#pragma unroll
      for (int kk = 0; kk < 2; ++kk) af[mi][kk] = rdA(cur, mi, kk);
#pragma unroll
    for (int n = 0; n < 2; ++n)
#pragma unroll
      for (int kk = 0; kk < 2; ++kk) bf[n][kk] = rdB(cur, n, kk);
    if (pf) {  // issue ALL of next tile's staging here: max latency cover
      stageA(nxt, 0, t + 1); stageB(nxt, 0, t + 1);
      stageA(nxt, 1, t + 1); stageB(nxt, 1, t + 1);
      stageB(nxt, 2, t + 1); stageB(nxt, 3, t + 1);
    }
    __builtin_amdgcn_sched_barrier(0);
    __builtin_amdgcn_s_setprio(1);
#pragma unroll
    for (int mi = 0; mi < 2; ++mi)
#pragma unroll
      for (int n = 0; n < 2; ++n)
#pragma unroll
        for (int kk = 0; kk < 2; ++kk)
          acc[mi][n] = __builtin_amdgcn_mfma_f32_16x16x32_bf16(
              af[mi][kk], bf[n][kk], acc[mi][n], 0, 0, 0);
    __builtin_amdgcn_s_setprio(0);

    // ---- phase 1: mh=0, nh=1 ----
#pragma unroll
    for (int n = 2; n < 4; ++n)
#pragma unroll
      for (int kk = 0; kk < 2; ++kk) bf[n][kk] = rdB(cur, n, kk);
    __builtin_amdgcn_sched_barrier(0);
    __builtin_amdgcn_s_setprio(1);
#pragma unroll
    for (int mi = 0; mi < 2; ++mi)
#pragma unroll
      for (int n = 2; n < 4; ++n)
#pragma unroll
        for (int kk = 0; kk < 2; ++kk)
          acc[mi][n] = __builtin_amdgcn_mfma_f32_16x16x32_bf16(
              af[mi][kk], bf[n][kk], acc[mi][n], 0, 0, 0);
    __builtin_amdgcn_s_setprio(0);

    // ---- phase 2: mh=1, nh=0 ----
#pragma unroll
    for (int mi = 0; mi < 2; ++mi)
#pragma unroll
      for (int kk = 0; kk < 2; ++kk) af[mi][kk] = rdA(cur, 2 + mi, kk);
    __builtin_amdgcn_sched_barrier(0);
    __builtin_amdgcn_s_setprio(1);
#pragma unroll
    for (int mi = 0; mi < 2; ++mi)
#pragma unroll
      for (int n = 0; n < 2; ++n)
#pragma unroll
        for (int kk = 0; kk < 2; ++kk)
          acc[2 + mi][n] = __builtin_amdgcn_mfma_f32_16x16x32_bf16(
              af[mi][kk], bf[n][kk], acc[2 + mi][n], 0, 0, 0);
    __builtin_amdgcn_s_setprio(0);

    // ---- phase 3: mh=1, nh=1 ----
    __builtin_amdgcn_s_setprio(1);
#pragma unroll
    for (int mi = 0; mi < 2; ++mi)
#pragma unroll
      for (int n = 2; n < 4; ++n)
#pragma unroll
        for (int kk = 0; kk < 2; ++kk)
          acc[2 + mi][n] = __builtin_amdgcn_mfma_f32_16x16x32_bf16(
              af[mi][kk], bf[n][kk], acc[2 + mi][n], 0, 0, 0);
    __builtin_amdgcn_s_setprio(0);

    // ---- gate: next tile's staging landed (own) + collective barrier ----
    if (pf) asm volatile("s_waitcnt vmcnt(0)" ::: "memory");
    __builtin_amdgcn_s_barrier();
    __builtin_amdgcn_sched_barrier(0);
    cur = nxt;
  }

  // ---- epilogue ----
  const int r0 = (lane >> 4) * 4;
  const int cl = lane & 15;
  if constexpr (EPI == 1) {
#pragma unroll
    for (int n = 0; n < 4; ++n) {
      int colg = cn0 + wc * 64 + n * 16 + cl;
      int e = (colg < 4096) ? (colg >> 9) : (8 + ((colg - 4096) >> 10));
#pragma unroll
      for (int m = 0; m < 4; ++m) {
        int rl = wr * 64 + m * 16 + r0;
#pragma unroll
        for (int r = 0; r < 4; ++r) {
          float v = gelu_f(acc[m][n][r]) * Cw[(rl + r) * 16 + e];
          hout[(size_t)(rm0 + rl + r) * W_TOT + colg] = f2bf(v);
        }
      }
    }
  } else {
    float* pz = pout + (size_t)blockIdx.z * T_TOK * D_EMB;
#pragma unroll
    for (int n = 0; n < 4; ++n) {
      int colg = cn0 + wc * 64 + n * 16 + cl;
#pragma unroll
      for (int m = 0; m < 4; ++m) {
        int rl = wr * 64 + m * 16 + r0;
#pragma unroll
        for (int r = 0; r < 4; ++r)
          pz[(size_t)(rm0 + rl + r) * D_EMB + colg] = acc[m][n][r];
      }
    }
  }
}

__global__ __launch_bounds__(256) void reduce_kernel(
    const float* __restrict__ partial, float* __restrict__ out, int splits) {
  int i = (blockIdx.x * 256 + threadIdx.x) * 4;
  if (i >= T_TOK * D_EMB) return;
  float4 s = *(const float4*)(partial + i);
  for (int sp = 1; sp < splits; ++sp) {
    float4 v = *(const float4*)(partial + (size_t)sp * T_TOK * D_EMB + i);
    s.x += v.x; s.y += v.y; s.z += v.z; s.w += v.w;
  }
  *(float4*)(out + i) = s;
}

// ---------------- launcher ----------------

extern "C" void kernel_launch(void* const* d_in, const int* in_sizes, int n_in,
                              void* d_out, int out_size, void* d_ws, size_t ws_size,
                              hipStream_t stream) {
  const float* x = (const float*)d_in[0];
  const float* router_w = (const float*)d_in[1];
  const float* w1 = (const float*)d_in[2];
  const float* w2 = (const float*)d_in[3];
  float* out = (float*)d_out;

  char* ws = (char*)d_ws;
  size_t off = 0;
  auto alloc = [&](size_t bytes) {
    char* p = ws + off;
    off += (bytes + 255) & ~(size_t)255;
    return p;
  };
  unsigned short* xb  = (unsigned short*)alloc((size_t)T_TOK * D_EMB * 2);
  unsigned short* w1t = (unsigned short*)alloc((size_t)W_TOT * D_EMB * 2);
  unsigned short* w2t = (unsigned short*)alloc((size_t)D_EMB * W_TOT * 2);
  unsigned short* h   = (unsigned short*)alloc((size_t)T_TOK * W_TOT * 2);
  float* comb         = (float*)alloc((size_t)T_TOK * N_EXP * 4);

  // split-K for GEMM2 (divisors of 192 K-tiles); partial fp32 per split
  int splits = 1;
  {
    size_t remain = (ws_size > off) ? ws_size - off : 0;
    const int cand[3] = {4, 3, 2};
    for (int c = 0; c < 3; ++c) {
      if ((size_t)cand[c] * T_TOK * D_EMB * 4 <= remain) { splits = cand[c]; break; }
    }
  }
  float* partial = (splits > 1) ? (float*)alloc((size_t)splits * T_TOK * D_EMB * 4) : out;
  int kchunk = W_TOT / splits;

  cvt_bf16_kernel<<<(T_TOK * D_EMB) / 1024, 256, 0, stream>>>(x, xb, T_TOK * D_EMB);
  transpose_cvt_kernel<<<dim3(W_TOT / 32, D_EMB / 32), 256, 0, stream>>>(w1, w1t, D_EMB, W_TOT);
  transpose_cvt_kernel<<<dim3(D_EMB / 32, W_TOT / 32), 256, 0, stream>>>(w2, w2t, W_TOT, D_EMB);
  router_kernel<<<T_TOK / 4, 256, 0, stream>>>(x, router_w, comb);

  // GEMM1: H = gelu(X W1) * comb   (A=xb [2048][768], B=w1t [12288][768])
  gemm8p_kernel<1><<<dim3(W_TOT / 256, T_TOK / 128, 1), 512, 0, stream>>>(
      xb, w1t, D_EMB, D_EMB, D_EMB / 64, D_EMB, comb, h, nullptr);

  // GEMM2: OUT = H W2   (A=h [2048][12288], B=w2t [768][12288]), split-K
  gemm8p_kernel<0><<<dim3(D_EMB / 256, T_TOK / 128, splits), 512, 0, stream>>>(
      h, w2t, W_TOT, W_TOT, kchunk / 64, kchunk, nullptr, nullptr, partial);

  if (splits > 1)
    reduce_kernel<<<(T_TOK * D_EMB) / 1024, 256, 0, stream>>>(partial, out, splits);
}

// Round 3
// 162.972 us; speedup vs baseline: 1.0914x; 1.0914x over previous
//
#include <hip/hip_runtime.h>
#include <hip/hip_bf16.h>

// MoE MLP: x[1,2048,768] fp32, router_w[16,768], w1[768,12288], w2[12288,768]
// out[1,2048,768] fp32.  Experts: 8x512 + 8x1024, top-8, normalized.
// Dense bf16 GEMMs (reference is dense+masked); comb folded into H.
// GEMM core: 256x256 tile, BK=64, 8 waves (2Mx4N, 128x64/wave), dbuf LDS,
// 4-phase/K-tile, XOR-swizzled LDS (T2), setprio (T5), XCD-ownership mapping
// (T1): each XCD owns a few B-panels so staging hits its private L2.

#define T_TOK 2048
#define D_EMB 768
#define W_TOT 12288
#define N_EXP 16

typedef __attribute__((ext_vector_type(4))) float f32x4;
typedef __attribute__((ext_vector_type(8))) short bf16x8;

typedef __attribute__((address_space(1))) const unsigned int as1c_u32;
typedef __attribute__((address_space(3))) unsigned int as3_u32;

__device__ __forceinline__ void gload16(const void* g, void* l) {
  __builtin_amdgcn_global_load_lds((as1c_u32*)g, (as3_u32*)l, 16, 0, 0);
}

__device__ __forceinline__ unsigned short f2bf(float f) {
  __hip_bfloat16 h = __float2bfloat16(f);
  return *reinterpret_cast<unsigned short*>(&h);
}

__device__ __forceinline__ float gelu_f(float x) {
  // jax.nn.gelu default (approximate=True, tanh form)
  float x3 = x * x * x;
  float a = 0.7978845608028654f * __builtin_fmaf(0.044715f, x3, x);
  a = fminf(fmaxf(a, -20.f), 20.f);
  float e = __expf(-2.0f * a);
  float t = (1.0f - e) / (1.0f + e);
  return 0.5f * x * (1.0f + t);
}

// ---------------- conversion kernels ----------------

__global__ __launch_bounds__(256) void cvt_bf16_kernel(
    const float* __restrict__ in, unsigned short* __restrict__ out, int n) {
  int i = (blockIdx.x * 256 + threadIdx.x) * 4;
  if (i >= n) return;
  float4 v = *(const float4*)(in + i);
  ushort4 o;
  o.x = f2bf(v.x); o.y = f2bf(v.y); o.z = f2bf(v.z); o.w = f2bf(v.w);
  *(ushort4*)(out + i) = o;
}

// in fp32 [R][C] -> out bf16 [C][R]
__global__ __launch_bounds__(256) void transpose_cvt_kernel(
    const float* __restrict__ in, unsigned short* __restrict__ out, int R, int C) {
  __shared__ float tile[32][33];
  int c0 = blockIdx.x * 32;
  int r0 = blockIdx.y * 32;
  int i = threadIdx.x;
  {
    int r = i >> 3, c4 = (i & 7) * 4;
    float4 v = *(const float4*)(in + (size_t)(r0 + r) * C + c0 + c4);
    tile[r][c4 + 0] = v.x; tile[r][c4 + 1] = v.y;
    tile[r][c4 + 2] = v.z; tile[r][c4 + 3] = v.w;
  }
  __syncthreads();
  {
    int c = i >> 3, r4 = (i & 7) * 4;
    ushort4 o;
    o.x = f2bf(tile[r4 + 0][c]);
    o.y = f2bf(tile[r4 + 1][c]);
    o.z = f2bf(tile[r4 + 2][c]);
    o.w = f2bf(tile[r4 + 3][c]);
    *(ushort4*)(out + (size_t)(c0 + c) * R + r0 + r4) = o;
  }
}

// ---------------- router ----------------

__global__ __launch_bounds__(256) void router_kernel(
    const float* __restrict__ x, const float* __restrict__ rw,
    float* __restrict__ comb) {
  int tid = threadIdx.x, lane = tid & 63, w = tid >> 6;
  int t = blockIdx.x * 4 + w;
  const float* xr = x + (size_t)t * D_EMB;
  float xv[12];
#pragma unroll
  for (int i = 0; i < 12; ++i) xv[i] = xr[lane + 64 * i];
  float lg[16];
#pragma unroll
  for (int e = 0; e < 16; ++e) {
    const float* we = rw + (size_t)e * D_EMB;
    float p = 0.f;
#pragma unroll
    for (int i = 0; i < 12; ++i) p = __builtin_fmaf(xv[i], we[lane + 64 * i], p);
#pragma unroll
    for (int off = 32; off >= 1; off >>= 1) p += __shfl_xor(p, off, 64);
    lg[e] = p;
  }
  float mx = lg[0];
#pragma unroll
  for (int e = 1; e < 16; ++e) mx = fmaxf(mx, lg[e]);
  float ex[16];
#pragma unroll
  for (int e = 0; e < 16; ++e) ex[e] = __expf(lg[e] - mx);
  float selsum = 0.f, myval = 0.f;
#pragma unroll
  for (int e = 0; e < 16; ++e) {
    int rank = 0;
#pragma unroll
    for (int e2 = 0; e2 < 16; ++e2)
      rank += (ex[e2] > ex[e]) || (ex[e2] == ex[e] && e2 < e);
    bool sel = rank < 8;
    float v = sel ? ex[e] : 0.f;
    selsum += v;
    if (e == lane) myval = v;
  }
  if (lane < 16) comb[(size_t)t * N_EXP + lane] = myval / selsum;
}

// ---------------- unified 8-wave pipelined GEMM core, 256x256 ----------------
// C[256][256] per block; A row-major [M][lda], B N-major [N][ldb] (bf16,
// K contiguous). 8 waves = 2(M) x 4(N); per-wave 128x64 output.
// NN = number of N-tiles (for block-id decode). swz: XCD-ownership mapping.
// EPI==1: H = gelu(acc) * comb (bf16).  EPI==0: fp32 partial store.

template <int EPI, int NN>
__global__ __launch_bounds__(512, 2) void gemm8p_kernel(
    const unsigned short* __restrict__ Ag, const unsigned short* __restrict__ Bg,
    int lda, int ldb, int ntiles, int kchunk, int swz,
    const float* __restrict__ comb, unsigned short* __restrict__ hout,
    float* __restrict__ pout) {
  __shared__ __align__(16) char Ash[2][32768];   // [256 rows][64 k] bf16
  __shared__ __align__(16) char Bsh[2][32768];   // [256 rows][64 k] bf16
  __shared__ float Cw[EPI ? 256 * 16 : 16];

  const int tid = threadIdx.x;
  const int lane = tid & 63;
  const int wid = tid >> 6;
  const int wr = wid >> 2;        // 0..1  (M half: 128 rows)
  const int wc = wid & 3;         // 0..3  (N quarter: 64 cols)

  // ---- block-id decode: XCD gets a contiguous group of (n, z) columns,
  // iterating M fastest, so its concurrent blocks share few B-panels (L2-fit).
  int mt, nt, zt;
  {
    int bid = blockIdx.x;
    if (swz) {
      int xcd = bid & 7, r = bid >> 3;
      int m = r & 7, c = r >> 3;
      int gpx = (int)(gridDim.x >> 6);       // col-groups per XCD
      int combo = xcd * gpx + c;
      mt = m; nt = combo % NN; zt = combo / NN;
    } else {
      nt = bid % NN; int t2 = bid / NN; mt = t2 & 7; zt = t2 >> 3;
    }
  }
  const int rm0 = mt * 256;
  const int cn0 = nt * 256;
  const int kbeg = zt * kchunk;

  if constexpr (EPI == 1) {
    int row = tid >> 1, c8 = (tid & 1) * 8;
    *(float4*)&Cw[row * 16 + c8] =
        *(const float4*)(comb + (size_t)(rm0 + row) * N_EXP + c8);
    *(float4*)&Cw[row * 16 + c8 + 4] =
        *(const float4*)(comb + (size_t)(rm0 + row) * N_EXP + c8 + 4);
  }

  // ---- staging (pre-swizzled global source, linear LDS dest; rule #21) ----
  auto stage = [&](const unsigned short* base, int ld, int row0,
                   char* ldsbase, int j, int kt) {
    int off = j * 8192 + tid * 16;
    int row = off >> 7, inrow = off & 127;
    int scol = inrow ^ ((row & 7) << 4);
    const char* src = (const char*)base +
        ((size_t)(row0 + row) * ld + (kbeg + kt * 64)) * 2 + scol;
    gload16(src, ldsbase + j * 8192 + wid * 1024);
  };
  auto rdA = [&](int buf, int m, int kk) {
    int row = wr * 128 + m * 16 + (lane & 15);
    int col = (kk * 64 + (lane >> 4) * 16) ^ ((row & 7) << 4);
    return *(const bf16x8*)(Ash[buf] + row * 128 + col);
  };
  auto rdB = [&](int buf, int n, int kk) {
    int row = wc * 64 + n * 16 + (lane & 15);
    int col = (kk * 64 + (lane >> 4) * 16) ^ ((row & 7) << 4);
    return *(const bf16x8*)(Bsh[buf] + row * 128 + col);
  };

  f32x4 acc[8][4];
#pragma unroll
  for (int m = 0; m < 8; ++m)
#pragma unroll
    for (int n = 0; n < 4; ++n) acc[m][n] = (f32x4){0.f, 0.f, 0.f, 0.f};

  // prologue: stage tile 0 into buf 0
#pragma unroll
  for (int j = 0; j < 4; ++j) stage(Ag, lda, rm0, Ash[0], j, 0);
#pragma unroll
  for (int j = 0; j < 4; ++j) stage(Bg, ldb, cn0, Bsh[0], j, 0);
  asm volatile("s_waitcnt vmcnt(0) lgkmcnt(0)" ::: "memory");
  __builtin_amdgcn_s_barrier();
  __builtin_amdgcn_sched_barrier(0);

  int cur = 0;
  for (int t = 0; t < ntiles; ++t) {
    const int nxt = cur ^ 1;
    const bool pf = (t + 1 < ntiles);
    bf16x8 af[4][2], bf[4][2];

    // ---- phase 0: m 0..3 x n 0..1 ; issue next A staging ----
#pragma unroll
    for (int mi = 0; mi < 4; ++mi)
#pragma unroll
      for (int kk = 0; kk < 2; ++kk) af[mi][kk] = rdA(cur, mi, kk);
#pragma unroll
    for (int n = 0; n < 2; ++n)
#pragma unroll
      for (int kk = 0; kk < 2; ++kk) bf[n][kk] = rdB(cur, n, kk);
    if (pf) {
#pragma unroll
      for (int j = 0; j < 4; ++j) stage(Ag, lda, rm0, Ash[nxt], j, t + 1);
    }
    __builtin_amdgcn_sched_barrier(0);
    __builtin_amdgcn_s_setprio(1);
#pragma unroll
    for (int mi = 0; mi < 4; ++mi)
#pragma unroll
      for (int n = 0; n < 2; ++n)
#pragma unroll
        for (int kk = 0; kk < 2; ++kk)
          acc[mi][n] = __builtin_amdgcn_mfma_f32_16x16x32_bf16(
              af[mi][kk], bf[n][kk], acc[mi][n], 0, 0, 0);
    __builtin_amdgcn_s_setprio(0);

    // ---- phase 1: m 0..3 x n 2..3 ; issue next B staging ----
#pragma unroll
    for (int n = 2; n < 4; ++n)
#pragma unroll
      for (int kk = 0; kk < 2; ++kk) bf[n][kk] = rdB(cur, n, kk);
    if (pf) {
#pragma unroll
      for (int j = 0; j < 4; ++j) stage(Bg, ldb, cn0, Bsh[nxt], j, t + 1);
    }
    __builtin_amdgcn_sched_barrier(0);
    __builtin_amdgcn_s_setprio(1);
#pragma unroll
    for (int mi = 0; mi < 4; ++mi)
#pragma unroll
      for (int n = 2; n < 4; ++n)
#pragma unroll
        for (int kk = 0; kk < 2; ++kk)
          acc[mi][n] = __builtin_amdgcn_mfma_f32_16x16x32_bf16(
              af[mi][kk], bf[n][kk], acc[mi][n], 0, 0, 0);
    __builtin_amdgcn_s_setprio(0);

    // ---- phase 2: m 4..7 x n 0..1 ----
#pragma unroll
    for (int mi = 0; mi < 4; ++mi)
#pragma unroll
      for (int kk = 0; kk < 2; ++kk) af[mi][kk] = rdA(cur, 4 + mi, kk);
    __builtin_amdgcn_sched_barrier(0);
    __builtin_amdgcn_s_setprio(1);
#pragma unroll
    for (int mi = 0; mi < 4; ++mi)
#pragma unroll
      for (int n = 0; n < 2; ++n)
#pragma unroll
        for (int kk = 0; kk < 2; ++kk)
          acc[4 + mi][n] = __builtin_amdgcn_mfma_f32_16x16x32_bf16(
              af[mi][kk], bf[n][kk], acc[4 + mi][n], 0, 0, 0);
    __builtin_amdgcn_s_setprio(0);

    // ---- phase 3: m 4..7 x n 2..3 ----
    __builtin_amdgcn_s_setprio(1);
#pragma unroll
    for (int mi = 0; mi < 4; ++mi)
#pragma unroll
      for (int n = 2; n < 4; ++n)
#pragma unroll
        for (int kk = 0; kk < 2; ++kk)
          acc[4 + mi][n] = __builtin_amdgcn_mfma_f32_16x16x32_bf16(
              af[mi][kk], bf[n][kk], acc[4 + mi][n], 0, 0, 0);
    __builtin_amdgcn_s_setprio(0);

    // ---- gate: next tile staged + everyone done reading cur ----
    if (pf) asm volatile("s_waitcnt vmcnt(0)" ::: "memory");
    __builtin_amdgcn_s_barrier();
    __builtin_amdgcn_sched_barrier(0);
    cur = nxt;
  }

  // ---- epilogue ----
  const int r0 = (lane >> 4) * 4;
  const int cl = lane & 15;
  if constexpr (EPI == 1) {
#pragma unroll
    for (int n = 0; n < 4; ++n) {
      int colg = cn0 + wc * 64 + n * 16 + cl;
      int e = (colg < 4096) ? (colg >> 9) : (8 + ((colg - 4096) >> 10));
#pragma unroll
      for (int m = 0; m < 8; ++m) {
        int rl = wr * 128 + m * 16 + r0;
#pragma unroll
        for (int r = 0; r < 4; ++r) {
          float v = gelu_f(acc[m][n][r]) * Cw[(rl + r) * 16 + e];
          hout[(size_t)(rm0 + rl + r) * W_TOT + colg] = f2bf(v);
        }
      }
    }
  } else {
    float* pz = pout + (size_t)zt * T_TOK * D_EMB;
#pragma unroll
    for (int n = 0; n < 4; ++n) {
      int colg = cn0 + wc * 64 + n * 16 + cl;
#pragma unroll
      for (int m = 0; m < 8; ++m) {
        int rl = wr * 128 + m * 16 + r0;
#pragma unroll
        for (int r = 0; r < 4; ++r)
          pz[(size_t)(rm0 + rl + r) * D_EMB + colg] = acc[m][n][r];
      }
    }
  }
}

__global__ __launch_bounds__(256) void reduce_kernel(
    const float* __restrict__ partial, float* __restrict__ out, int splits) {
  int i = (blockIdx.x * 256 + threadIdx.x) * 4;
  if (i >= T_TOK * D_EMB) return;
  float4 s = *(const float4*)(partial + i);
  for (int sp = 1; sp < splits; ++sp) {
    float4 v = *(const float4*)(partial + (size_t)sp * T_TOK * D_EMB + i);
    s.x += v.x; s.y += v.y; s.z += v.z; s.w += v.w;
  }
  *(float4*)(out + i) = s;
}

// ---------------- launcher ----------------

extern "C" void kernel_launch(void* const* d_in, const int* in_sizes, int n_in,
                              void* d_out, int out_size, void* d_ws, size_t ws_size,
                              hipStream_t stream) {
  const float* x = (const float*)d_in[0];
  const float* router_w = (const float*)d_in[1];
  const float* w1 = (const float*)d_in[2];
  const float* w2 = (const float*)d_in[3];
  float* out = (float*)d_out;

  char* ws = (char*)d_ws;
  size_t off = 0;
  auto alloc = [&](size_t bytes) {
    char* p = ws + off;
    off += (bytes + 255) & ~(size_t)255;
    return p;
  };
  unsigned short* xb  = (unsigned short*)alloc((size_t)T_TOK * D_EMB * 2);
  unsigned short* w1t = (unsigned short*)alloc((size_t)W_TOT * D_EMB * 2);
  unsigned short* w2t = (unsigned short*)alloc((size_t)D_EMB * W_TOT * 2);
  unsigned short* h   = (unsigned short*)alloc((size_t)T_TOK * W_TOT * 2);
  float* comb         = (float*)alloc((size_t)T_TOK * N_EXP * 4);

  // split-K for GEMM2 (prefer 8: 192 blocks + clean XCD ownership mapping)
  int splits = 1;
  {
    size_t remain = (ws_size > off) ? ws_size - off : 0;
    const int cand[5] = {8, 6, 4, 3, 2};
    for (int c = 0; c < 5; ++c) {
      if ((size_t)cand[c] * T_TOK * D_EMB * 4 <= remain) { splits = cand[c]; break; }
    }
  }
  float* partial = (splits > 1) ? (float*)alloc((size_t)splits * T_TOK * D_EMB * 4) : out;
  int kchunk = W_TOT / splits;

  cvt_bf16_kernel<<<(T_TOK * D_EMB) / 1024, 256, 0, stream>>>(x, xb, T_TOK * D_EMB);
  transpose_cvt_kernel<<<dim3(W_TOT / 32, D_EMB / 32), 256, 0, stream>>>(w1, w1t, D_EMB, W_TOT);
  transpose_cvt_kernel<<<dim3(D_EMB / 32, W_TOT / 32), 256, 0, stream>>>(w2, w2t, W_TOT, D_EMB);
  router_kernel<<<T_TOK / 4, 256, 0, stream>>>(x, router_w, comb);

  // GEMM1: H = gelu(X W1) * comb ; grid 384 (48 N-tiles x 8 M-tiles), swz ok
  gemm8p_kernel<1, 48><<<384, 512, 0, stream>>>(
      xb, w1t, D_EMB, D_EMB, D_EMB / 64, D_EMB, 1, comb, h, nullptr);

  // GEMM2: OUT = H W2 ; grid 24*splits (3 N x 8 M x splits)
  {
    int grid = 24 * splits;
    int swz = (grid % 64 == 0) ? 1 : 0;   // decode needs gridDim%64==0
    gemm8p_kernel<0, 3><<<grid, 512, 0, stream>>>(
        h, w2t, W_TOT, W_TOT, kchunk / 64, kchunk, swz, nullptr, nullptr, partial);
  }

  if (splits > 1)
    reduce_kernel<<<(T_TOK * D_EMB) / 1024, 256, 0, stream>>>(partial, out, splits);
}

// Round 5
// 142.704 us; speedup vs baseline: 1.2464x; 1.1420x over previous
//
#include <hip/hip_runtime.h>
#include <hip/hip_bf16.h>

// MoE MLP: x[1,2048,768] fp32, router_w[16,768], w1[768,12288], w2[12288,768]
// out[1,2048,768] fp32.  Experts: 8x512 + 8x1024, top-8, normalized.
// Dense bf16 GEMMs (reference is dense+masked); comb folded into H.
// GEMM core: 256x192 tile, BK=64, 8 waves (2Mx4N, 128x48/wave), dbuf LDS,
// 2-phase/K-tile with COUNTED vmcnt (T4: never drain to 0 in the main loop),
// XOR-swizzled LDS (T2), setprio (T5), XCD-ownership block mapping (T1).

#define T_TOK 2048
#define D_EMB 768
#define W_TOT 12288
#define N_EXP 16

typedef __attribute__((ext_vector_type(4))) float f32x4;
typedef __attribute__((ext_vector_type(8))) short bf16x8;

typedef __attribute__((address_space(1))) const unsigned int as1c_u32;
typedef __attribute__((address_space(3))) unsigned int as3_u32;

__device__ __forceinline__ void gload16(const void* g, void* l) {
  __builtin_amdgcn_global_load_lds((as1c_u32*)g, (as3_u32*)l, 16, 0, 0);
}

__device__ __forceinline__ unsigned short f2bf(float f) {
  __hip_bfloat16 h = __float2bfloat16(f);
  return *reinterpret_cast<unsigned short*>(&h);
}

__device__ __forceinline__ float gelu_f(float x) {
  // jax.nn.gelu default (approximate=True, tanh form)
  float x3 = x * x * x;
  float a = 0.7978845608028654f * __builtin_fmaf(0.044715f, x3, x);
  a = fminf(fmaxf(a, -20.f), 20.f);
  float e = __expf(-2.0f * a);
  float t = (1.0f - e) / (1.0f + e);
  return 0.5f * x * (1.0f + t);
}

// ---------------- conversion kernels ----------------

__global__ __launch_bounds__(256) void cvt_bf16_kernel(
    const float* __restrict__ in, unsigned short* __restrict__ out, int n) {
  int i = (blockIdx.x * 256 + threadIdx.x) * 4;
  if (i >= n) return;
  float4 v = *(const float4*)(in + i);
  ushort4 o;
  o.x = f2bf(v.x); o.y = f2bf(v.y); o.z = f2bf(v.z); o.w = f2bf(v.w);
  *(ushort4*)(out + i) = o;
}

// in fp32 [R][C] -> out bf16 [C][R]
__global__ __launch_bounds__(256) void transpose_cvt_kernel(
    const float* __restrict__ in, unsigned short* __restrict__ out, int R, int C) {
  __shared__ float tile[32][33];
  int c0 = blockIdx.x * 32;
  int r0 = blockIdx.y * 32;
  int i = threadIdx.x;
  {
    int r = i >> 3, c4 = (i & 7) * 4;
    float4 v = *(const float4*)(in + (size_t)(r0 + r) * C + c0 + c4);
    tile[r][c4 + 0] = v.x; tile[r][c4 + 1] = v.y;
    tile[r][c4 + 2] = v.z; tile[r][c4 + 3] = v.w;
  }
  __syncthreads();
  {
    int c = i >> 3, r4 = (i & 7) * 4;
    ushort4 o;
    o.x = f2bf(tile[r4 + 0][c]);
    o.y = f2bf(tile[r4 + 1][c]);
    o.z = f2bf(tile[r4 + 2][c]);
    o.w = f2bf(tile[r4 + 3][c]);
    *(ushort4*)(out + (size_t)(c0 + c) * R + r0 + r4) = o;
  }
}

// ---------------- router ----------------

__global__ __launch_bounds__(256) void router_kernel(
    const float* __restrict__ x, const float* __restrict__ rw,
    float* __restrict__ comb) {
  int tid = threadIdx.x, lane = tid & 63, w = tid >> 6;
  int t = blockIdx.x * 4 + w;
  const float* xr = x + (size_t)t * D_EMB;
  float xv[12];
#pragma unroll
  for (int i = 0; i < 12; ++i) xv[i] = xr[lane + 64 * i];
  float lg[16];
#pragma unroll
  for (int e = 0; e < 16; ++e) {
    const float* we = rw + (size_t)e * D_EMB;
    float p = 0.f;
#pragma unroll
    for (int i = 0; i < 12; ++i) p = __builtin_fmaf(xv[i], we[lane + 64 * i], p);
#pragma unroll
    for (int off = 32; off >= 1; off >>= 1) p += __shfl_xor(p, off, 64);
    lg[e] = p;
  }
  float mx = lg[0];
#pragma unroll
  for (int e = 1; e < 16; ++e) mx = fmaxf(mx, lg[e]);
  float ex[16];
#pragma unroll
  for (int e = 0; e < 16; ++e) ex[e] = __expf(lg[e] - mx);
  float selsum = 0.f, myval = 0.f;
#pragma unroll
  for (int e = 0; e < 16; ++e) {
    int rank = 0;
#pragma unroll
    for (int e2 = 0; e2 < 16; ++e2)
      rank += (ex[e2] > ex[e]) || (ex[e2] == ex[e] && e2 < e);
    bool sel = rank < 8;
    float v = sel ? ex[e] : 0.f;
    selsum += v;
    if (e == lane) myval = v;
  }
  if (lane < 16) comb[(size_t)t * N_EXP + lane] = myval / selsum;
}

// ------------- 8-wave counted-vmcnt pipelined GEMM, 256x192 -------------
// C[256][192] per block; A row-major [M][lda], B N-major [N][ldb] (bf16,
// K contiguous). 8 waves = 2(M) x 4(N); per-wave 128x48 output.
// Per K-tile: 7 staging loads in fixed order [B0,B1,B2,A0,A2 | A1,A3];
// phase P0 waits vmcnt(2) (oldest 5 = B*,A0,A2 landed), P1 waits vmcnt(5)
// (A1,A3 landed). Loads issued in tile t are consumed in tile t+1.
// MAP: 0 = gemm1 XCD-owns-N (grid 512), 1 = gemm2 XCD=zt (grid 256),
//      2 = generic fallback. EPI: 1 = gelu*comb -> bf16 H, 0 = fp32 partial.

template <int EPI, int MAP>
__global__ __launch_bounds__(512, 2) void gemm_kernel(
    const unsigned short* __restrict__ Ag, const unsigned short* __restrict__ Bg,
    int lda, int ldb, int ntiles, int kchunk, int nnt,
    const float* __restrict__ comb, unsigned short* __restrict__ hout,
    float* __restrict__ pout) {
  __shared__ __align__(16) char smem[114688];  // A 2x32KB + B 2x24KB

  const int tid = threadIdx.x;
  const int lane = tid & 63;
  const int wid = tid >> 6;
  const int wr = wid >> 2;        // 0..1  (M half: 128 rows)
  const int wc = wid & 3;         // 0..3  (N quarter: 48 cols)

  int mt, nt, zt;
  {
    int bid = blockIdx.x;
    if (MAP == 0) {               // gemm1: XCD owns 8 N-panels, M fastest
      int xcd = bid & 7, r = bid >> 3;
      nt = xcd * 8 + (r >> 3); mt = r & 7; zt = 0;
    } else if (MAP == 1) {        // gemm2: XCD = K-split
      zt = bid & 7; int r = bid >> 3;
      nt = r & 3; mt = r >> 2;
    } else {                      // generic
      nt = bid % nnt; int t2 = bid / nnt; mt = t2 & 7; zt = t2 >> 3;
    }
  }
  const int rm0 = mt * 256;
  const int cn0 = nt * 192;
  const int kbeg = zt * kchunk;

  // ---- staging (pre-swizzled global source, linear LDS dest; rule #21) ----
  auto stageA = [&](int buf, int j, int kt) {
    int off = j * 8192 + tid * 16;
    int row = off >> 7, inrow = off & 127;
    int scol = inrow ^ ((row & 7) << 4);
    const char* src = (const char*)Ag +
        ((size_t)(rm0 + row) * lda + (kbeg + kt * 64)) * 2 + scol;
    gload16(src, smem + buf * 32768 + j * 8192 + wid * 1024);
  };
  auto stageB = [&](int buf, int j, int kt) {
    int off = j * 8192 + tid * 16;
    int row = off >> 7, inrow = off & 127;
    int scol = inrow ^ ((row & 7) << 4);
    const char* src = (const char*)Bg +
        ((size_t)(cn0 + row) * ldb + (kbeg + kt * 64)) * 2 + scol;
    gload16(src, smem + 65536 + buf * 24576 + j * 8192 + wid * 1024);
  };
  auto rdA = [&](int buf, int m, int kk) {
    int row = wr * 128 + m * 16 + (lane & 15);
    int col = (kk * 64 + (lane >> 4) * 16) ^ ((row & 7) << 4);
    return *(const bf16x8*)(smem + buf * 32768 + row * 128 + col);
  };
  auto rdB = [&](int buf, int n, int kk) {
    int row = wc * 48 + n * 16 + (lane & 15);
    int col = (kk * 64 + (lane >> 4) * 16) ^ ((row & 7) << 4);
    return *(const bf16x8*)(smem + 65536 + buf * 24576 + row * 128 + col);
  };

  f32x4 acc[8][3];
#pragma unroll
  for (int m = 0; m < 8; ++m)
#pragma unroll
    for (int n = 0; n < 3; ++n) acc[m][n] = (f32x4){0.f, 0.f, 0.f, 0.f};

  // prologue: tile 0, same issue order as steady state
  stageB(0, 0, 0); stageB(0, 1, 0); stageB(0, 2, 0);
  stageA(0, 0, 0); stageA(0, 2, 0);
  stageA(0, 1, 0); stageA(0, 3, 0);
  __builtin_amdgcn_sched_barrier(0);

  int cur = 0;
  for (int t = 0; t < ntiles; ++t) {
    const int nxt = cur ^ 1;
    const int ktn = (t + 1 < ntiles) ? t + 1 : t;  // clamp: uniform counts
    bf16x8 af[4][2], bf[3][2];

    // ---- phase 0: m0-3 x all n ----
    asm volatile("s_waitcnt vmcnt(2)" ::: "memory");  // B*,A0,A2 of cur landed
    __builtin_amdgcn_s_barrier();
    __builtin_amdgcn_sched_barrier(0);
#pragma unroll
    for (int m = 0; m < 4; ++m)
#pragma unroll
      for (int kk = 0; kk < 2; ++kk) af[m][kk] = rdA(cur, m, kk);
#pragma unroll
    for (int n = 0; n < 3; ++n)
#pragma unroll
      for (int kk = 0; kk < 2; ++kk) bf[n][kk] = rdB(cur, n, kk);
    stageB(nxt, 0, ktn); stageB(nxt, 1, ktn); stageB(nxt, 2, ktn);
    stageA(nxt, 0, ktn); stageA(nxt, 2, ktn);
    __builtin_amdgcn_sched_barrier(0);
    __builtin_amdgcn_s_setprio(1);
#pragma unroll
    for (int m = 0; m < 4; ++m)
#pragma unroll
      for (int n = 0; n < 3; ++n)
#pragma unroll
        for (int kk = 0; kk < 2; ++kk)
          acc[m][n] = __builtin_amdgcn_mfma_f32_16x16x32_bf16(
              af[m][kk], bf[n][kk], acc[m][n], 0, 0, 0);
    __builtin_amdgcn_s_setprio(0);

    // ---- phase 1: m4-7 x all n ----
    asm volatile("s_waitcnt vmcnt(5)" ::: "memory");  // A1,A3 of cur landed
    __builtin_amdgcn_s_barrier();
    __builtin_amdgcn_sched_barrier(0);
#pragma unroll
    for (int m = 0; m < 4; ++m)
#pragma unroll
      for (int kk = 0; kk < 2; ++kk) af[m][kk] = rdA(cur, 4 + m, kk);
    stageA(nxt, 1, ktn); stageA(nxt, 3, ktn);
    __builtin_amdgcn_sched_barrier(0);
    __builtin_amdgcn_s_setprio(1);
#pragma unroll
    for (int m = 0; m < 4; ++m)
#pragma unroll
      for (int n = 0; n < 3; ++n)
#pragma unroll
        for (int kk = 0; kk < 2; ++kk)
          acc[4 + m][n] = __builtin_amdgcn_mfma_f32_16x16x32_bf16(
              af[m][kk], bf[n][kk], acc[4 + m][n], 0, 0, 0);
    __builtin_amdgcn_s_setprio(0);
    cur = nxt;
  }

  asm volatile("s_waitcnt vmcnt(0)" ::: "memory");  // drain tail loads
  __syncthreads();                                  // all waves out of loop

  // ---- epilogue ----
  const int r0 = (lane >> 4) * 4;
  const int cl = lane & 15;
  if constexpr (EPI == 1) {
    float* Cwf = (float*)smem;   // reuse staging LDS: [256 rows][16 experts]
    {
      int row = tid >> 1, c8 = (tid & 1) * 8;
      const float* s = comb + (size_t)(rm0 + row) * N_EXP + c8;
      *(float4*)&Cwf[row * 16 + c8] = *(const float4*)s;
      *(float4*)&Cwf[row * 16 + c8 + 4] = *(const float4*)(s + 4);
    }
    __syncthreads();
#pragma unroll
    for (int n = 0; n < 3; ++n) {
      int colg = cn0 + wc * 48 + n * 16 + cl;
      int e = (colg < 4096) ? (colg >> 9) : (8 + ((colg - 4096) >> 10));
#pragma unroll
      for (int m = 0; m < 8; ++m) {
        int rl = wr * 128 + m * 16 + r0;
#pragma unroll
        for (int r = 0; r < 4; ++r) {
          float v = gelu_f(acc[m][n][r]) * Cwf[(rl + r) * 16 + e];
          hout[(size_t)(rm0 + rl + r) * W_TOT + colg] = f2bf(v);
        }
      }
    }
  } else {
    float* pz = pout + (size_t)zt * T_TOK * D_EMB;
#pragma unroll
    for (int n = 0; n < 3; ++n) {
      int colg = cn0 + wc * 48 + n * 16 + cl;
#pragma unroll
      for (int m = 0; m < 8; ++m) {
        int rl = wr * 128 + m * 16 + r0;
#pragma unroll
        for (int r = 0; r < 4; ++r)
          pz[(size_t)(rm0 + rl + r) * D_EMB + colg] = acc[m][n][r];
      }
    }
  }
}

__global__ __launch_bounds__(256) void reduce_kernel(
    const float* __restrict__ partial, float* __restrict__ out, int splits) {
  int i = (blockIdx.x * 256 + threadIdx.x) * 4;
  if (i >= T_TOK * D_EMB) return;
  float4 s = *(const float4*)(partial + i);
  for (int sp = 1; sp < splits; ++sp) {
    float4 v = *(const float4*)(partial + (size_t)sp * T_TOK * D_EMB + i);
    s.x += v.x; s.y += v.y; s.z += v.z; s.w += v.w;
  }
  *(float4*)(out + i) = s;
}

// ---------------- launcher ----------------

extern "C" void kernel_launch(void* const* d_in, const int* in_sizes, int n_in,
                              void* d_out, int out_size, void* d_ws, size_t ws_size,
                              hipStream_t stream) {
  const float* x = (const float*)d_in[0];
  const float* router_w = (const float*)d_in[1];
  const float* w1 = (const float*)d_in[2];
  const float* w2 = (const float*)d_in[3];
  float* out = (float*)d_out;

  char* ws = (char*)d_ws;
  size_t off = 0;
  auto alloc = [&](size_t bytes) {
    char* p = ws + off;
    off += (bytes + 255) & ~(size_t)255;
    return p;
  };
  unsigned short* xb  = (unsigned short*)alloc((size_t)T_TOK * D_EMB * 2);
  unsigned short* w1t = (unsigned short*)alloc((size_t)W_TOT * D_EMB * 2);
  unsigned short* w2t = (unsigned short*)alloc((size_t)D_EMB * W_TOT * 2);
  unsigned short* h   = (unsigned short*)alloc((size_t)T_TOK * W_TOT * 2);
  float* comb         = (float*)alloc((size_t)T_TOK * N_EXP * 4);

  int splits = 8;
  if (off + (size_t)8 * T_TOK * D_EMB * 4 > ws_size) splits = 4;
  if (off + (size_t)4 * T_TOK * D_EMB * 4 > ws_size) splits = 2;
  float* partial = (float*)alloc((size_t)splits * T_TOK * D_EMB * 4);
  int kchunk = W_TOT / splits;

  cvt_bf16_kernel<<<(T_TOK * D_EMB) / 1024, 256, 0, stream>>>(x, xb, T_TOK * D_EMB);
  transpose_cvt_kernel<<<dim3(W_TOT / 32, D_EMB / 32), 256, 0, stream>>>(w1, w1t, D_EMB, W_TOT);
  transpose_cvt_kernel<<<dim3(D_EMB / 32, W_TOT / 32), 256, 0, stream>>>(w2, w2t, W_TOT, D_EMB);
  router_kernel<<<T_TOK / 4, 256, 0, stream>>>(x, router_w, comb);

  // GEMM1: H = gelu(X W1) * comb ; grid 512 = 8M x 64N (XCD owns 8 N-panels)
  gemm_kernel<1, 0><<<512, 512, 0, stream>>>(
      xb, w1t, D_EMB, D_EMB, D_EMB / 64, D_EMB, 64, comb, h, nullptr);

  // GEMM2: OUT = H W2 ; split-K
  if (splits == 8) {
    gemm_kernel<0, 1><<<256, 512, 0, stream>>>(
        h, w2t, W_TOT, W_TOT, kchunk / 64, kchunk, 4, nullptr, nullptr, partial);
  } else {
    gemm_kernel<0, 2><<<32 * splits, 512, 0, stream>>>(
        h, w2t, W_TOT, W_TOT, kchunk / 64, kchunk, 4, nullptr, nullptr, partial);
  }
  reduce_kernel<<<(T_TOK * D_EMB) / 1024, 256, 0, stream>>>(partial, out, splits);
}